// Round 15
// baseline (45.693 us; speedup 1.0000x reference)
//
#include <hip/hip_runtime.h>
#include <math.h>

#define HH 512
#define WW 512

typedef float f2 __attribute__((ext_vector_type(2)));
typedef float f4 __attribute__((ext_vector_type(4)));

// per-wave LDS slice layout (word offsets)
#define OY   0      // Ys   16 x 20 (y-128; y2 in place)        [0,320)
#define OCB  320    // CbD   8 x 12 (cb mean +128; cb2 in place)[320,416)
#define OCR  416    // CrD   8 x 12                              [416,512)
#define OCF  512    // CF cb full-res 16 x 20                    [512,832)
#define OCF2 832    // CF cr full-res 16 x 20                    [832,1152)
#define OSCR 512    // transpose scratch 6 x 68 (reuses CF)      [512,920)
#define OAB  1152   // basis 64                                  [1152,1216)
#define WSZ  1216   // 4864 B per wave -> 19456 B per 4-wave block

static __device__ __forceinline__ f4 vclamp01x255(f4 v) {
    f4 z = 0.f, one = 1.f;
    return __builtin_elementwise_max(__builtin_elementwise_min(v, one), z) * 255.f;
}

__device__ __constant__ float YTAB[64] = {
    16,11,10,16,24,40,51,61,
    12,12,14,19,26,58,60,55,
    14,13,16,24,40,57,69,56,
    14,17,22,29,51,87,80,62,
    18,22,37,56,68,109,103,77,
    24,35,55,64,81,104,113,92,
    49,64,78,87,103,121,120,101,
    72,92,95,98,112,100,103,99};
__device__ __constant__ float CTAB[64] = {
    17,18,24,47,99,99,99,99,
    18,21,26,66,99,99,99,99,
    24,26,56,99,99,99,99,99,
    47,66,99,99,99,99,99,99,
    99,99,99,99,99,99,99,99,
    99,99,99,99,99,99,99,99,
    99,99,99,99,99,99,99,99,
    99,99,99,99,99,99,99,99};

// WAVE-AUTONOMOUS: one wave = one 16x16 tile (4 Y + 1 Cb + 1 Cr blocks).
// 4 independent waves per 256-thread block, ZERO __syncthreads — wave-private
// LDS, DS ops in-order per wave (verified pattern from R8). 8 blocks/CU =
// 32 waves/CU (100% cap). Per wave: stage (64 lanes, f4), chroma means,
// DCT/quant/IDCT on 6 of 8 lane-groups (lane j = column j of its block,
// packed fmaf chains, basis wave-uniform via readfirstlane), output (64
// lanes, f4 nontemporal). Bit-critical pre-round math identical to verified
// R8/R10-R13: no-fma left-assoc color; paired chroma mean (s01+s23)/4;
// two ascending-k fmaf-chain einsum passes (BLAS sgemm semantics, fp32 T1);
// IEEE fp32 div by qt; rintf half-even; fp32 cube. Post-round relaxed.
__global__ __launch_bounds__(256) void jpeg_fused(const float* __restrict__ in,
                                                  float* __restrict__ out)
{
#pragma clang fp contract(off)
    __shared__ float Wall[4][WSZ];

    const int tid  = threadIdx.x;
    const int wid  = tid >> 6;
    const int lane = tid & 63;
    float* W = Wall[wid];

    const int t  = blockIdx.x * 4 + wid;   // tile id; block = 4 adjacent tiles
    const int b  = t >> 10;                // 1024 tiles per image
    const int th = (t >> 5) & 31;
    const int tw = t & 31;
    const int h0 = th * 16;
    const int w0 = tw * 16;
    const size_t plane = (size_t)HH * WW;

    // staging/output coords: lane -> (row, 4-col segment)
    const int srow = lane >> 2;            // 0..15
    const int sc4  = (lane & 3) * 4;       // 0,4,8,12
    const size_t gbase = ((size_t)b * 3 * HH + (size_t)(h0 + srow)) * WW + (w0 + sc4);

    // ---- issue global loads first (latency hidden by basis build below)
    f4 Lr = *(const f4*)(in + gbase);
    f4 Lg = *(const f4*)(in + gbase + plane);
    f4 Lb = *(const f4*)(in + gbase + 2 * plane);

    // ---- basis (np-exact: int mult, fp64 pi-mult/div, fp64 cos, fp32 cast)
    {
        int x = lane >> 3, u = lane & 7;
        double arg = (double)((2 * x + 1) * u) * 3.14159265358979323846 / 16.0;
        W[OAB + lane] = (float)cos(arg);
    }
    // basis pairs -> wave-uniform f2 (SGPRs); runs while loads are in flight
    f2 As2[32];
#pragma unroll
    for (int k = 0; k < 32; ++k) {
        As2[k][0] = __int_as_float(__builtin_amdgcn_readfirstlane(__float_as_int(W[OAB + 2 * k])));
        As2[k][1] = __int_as_float(__builtin_amdgcn_readfirstlane(__float_as_int(W[OAB + 2 * k + 1])));
    }

    // ---- stage: clip*255, YCbCr (noblas: left-assoc mul/add, NO fma)
    {
        f4 r0 = vclamp01x255(Lr), g0 = vclamp01x255(Lg), b0 = vclamp01x255(Lb);
        f4 y  = ((r0 * 0.299f)     + (g0 * 0.587f))     + (b0 * 0.114f);
        f4 cb = ((r0 * -0.168736f) + (g0 * -0.331264f)) + (b0 * 0.5f);
        f4 cr = ((r0 * 0.5f)       + (g0 * -0.418688f)) + (b0 * -0.081312f);
        cb = cb + 128.f;                   // +SHIFT1, separate rn add
        cr = cr + 128.f;
        y  = y - 128.f;                    // channel does blocks-128
        *(f4*)&W[OY   + srow * 20 + sc4] = y;
        *(f4*)&W[OCF  + srow * 20 + sc4] = cb;
        *(f4*)&W[OCF2 + srow * 20 + sc4] = cr;
    }
    asm volatile("" ::: "memory");         // phase fence (compiler-only)

    // ---- chroma means: paired (p00+p01)+(p10+p11), true-div by 4
    {
        int cy = lane >> 3, cx = lane & 7;
        int a0 = OCF + (2 * cy) * 20 + 2 * cx, a1 = a0 + 20;
        float s01 = W[a0] + W[a0 + 1];
        float s23 = W[a1] + W[a1 + 1];
        W[OCB + cy * 12 + cx] = (s01 + s23) / 4.0f;
        int c0 = OCF2 + (2 * cy) * 20 + 2 * cx, c1 = c0 + 20;
        float t01 = W[c0] + W[c0 + 1];
        float t23 = W[c1] + W[c1 + 1];
        W[OCR + cy * 12 + cx] = (t01 + t23) / 4.0f;
    }
    asm volatile("" ::: "memory");

    // ---- DCT / quantize / IDCT on 6 of 8 lane-groups
    const int g = lane >> 3, j = lane & 7;
    if (g < 6) {
        const bool isY = (g < 4);
        float* scr = &W[OSCR + g * 68];    // overwrites CF (means already read)

        float X[8];
        if (isY) {
            int by = g >> 1, bx = g & 1;
#pragma unroll
            for (int x = 0; x < 8; ++x) X[x] = W[OY + (by * 8 + x) * 20 + bx * 8 + j];
        } else {
            int ob = (g == 4) ? OCB : OCR;
#pragma unroll
            for (int x = 0; x < 8; ++x) X[x] = W[ob + x * 12 + j] - 128.f;
        }

        // pass1 (contract x): T1[y=j][u], ascending-x fmaf chains, packed
        f2 Tv[4];
#pragma unroll
        for (int m = 0; m < 4; ++m) {
            f2 a = {0.f, 0.f};
#pragma unroll
            for (int x = 0; x < 8; ++x) {
                f2 xx = {X[x], X[x]};
                a = __builtin_elementwise_fma(xx, As2[x * 4 + m], a);
            }
            Tv[m] = a;
        }
#pragma unroll
        for (int m = 0; m < 4; ++m) {
            scr[(2 * m) * 8 + j]     = Tv[m][0];
            scr[(2 * m + 1) * 8 + j] = Tv[m][1];
        }
        float Tt[8];
        {
            float4 a = *(const float4*)&scr[j * 8];
            float4 c = *(const float4*)&scr[j * 8 + 4];
            Tt[0] = a.x; Tt[1] = a.y; Tt[2] = a.z; Tt[3] = a.w;
            Tt[4] = c.x; Tt[5] = c.y; Tt[6] = c.z; Tt[7] = c.w;
        }
        // pass2 (contract y): raw[u=j][v], ascending-y packed chains
        float R[8];
#pragma unroll
        for (int m = 0; m < 4; ++m) {
            f2 a = {0.f, 0.f};
#pragma unroll
            for (int y = 0; y < 8; ++y) {
                f2 tt = {Tt[y], Tt[y]};
                a = __builtin_elementwise_fma(tt, As2[y * 4 + m], a);
            }
            R[2 * m] = a[0]; R[2 * m + 1] = a[1];
        }
        // quantize row u=j (bit-critical: IEEE div, rintf), dequant, *alpha2
        const float* QT = isY ? YTAB : CTAB;
        float qt[8];
        {
            float4 a = *(const float4*)&QT[j * 8];
            float4 c = *(const float4*)&QT[j * 8 + 4];
            qt[0] = a.x; qt[1] = a.y; qt[2] = a.z; qt[3] = a.w;
            qt[4] = c.x; qt[5] = c.y; qt[6] = c.z; qt[7] = c.w;
        }
        const float RC = 0.70710678118654752440f;
        float au = (j == 0) ? RC : 1.0f;
        float G[8];
#pragma unroll
        for (int v = 0; v < 8; ++v) {
            float av    = (v == 0) ? RC : 1.0f;
            float a2    = au * av;             // ALPHA2 fp32 product
            float scale = a2 * 0.25f;          // _SCALE
            float dct   = scale * R[v];
            float xq    = dct / qt[v];         // IEEE fp32 divide
            float rd    = rintf(xq);           // half-to-even
            float d     = xq - rd;
            float cube  = (d * d) * d;
            float qq    = rd + cube;
            float deq   = qq * qt[v];
            G[v] = deq * a2;
        }
#pragma unroll
        for (int v = 0; v < 8; ++v) scr[v * 8 + j] = G[v];
        float Gt[8];
        {
            float4 a = *(const float4*)&scr[j * 8];
            float4 c = *(const float4*)&scr[j * 8 + 4];
            Gt[0] = a.x; Gt[1] = a.y; Gt[2] = a.z; Gt[3] = a.w;
            Gt[4] = c.x; Gt[5] = c.y; Gt[6] = c.z; Gt[7] = c.w;
        }
        // IDCT pass1 (contract u): T2[x][v=j], packed over x pairs
        f2 T2v[4];
#pragma unroll
        for (int m = 0; m < 4; ++m) {
            f2 a = {0.f, 0.f};
#pragma unroll
            for (int u = 0; u < 8; ++u) {
                f2 gg = {Gt[u], Gt[u]};
                a = __builtin_elementwise_fma(gg, As2[u * 4 + m], a);
            }
            T2v[m] = a;
        }
#pragma unroll
        for (int m = 0; m < 4; ++m) {
            scr[(2 * m) * 8 + j]     = T2v[m][0];
            scr[(2 * m + 1) * 8 + j] = T2v[m][1];
        }
        float T2t[8];
        {
            float4 a = *(const float4*)&scr[j * 8];
            float4 c = *(const float4*)&scr[j * 8 + 4];
            T2t[0] = a.x; T2t[1] = a.y; T2t[2] = a.z; T2t[3] = a.w;
            T2t[4] = c.x; T2t[5] = c.y; T2t[6] = c.z; T2t[7] = c.w;
        }
        // IDCT pass2 (contract v): out[x=j][y] = 0.25*sum + 128, packed
        float O[8];
#pragma unroll
        for (int m = 0; m < 4; ++m) {
            f2 a = {0.f, 0.f};
#pragma unroll
            for (int v = 0; v < 8; ++v) {
                f2 tt = {T2t[v], T2t[v]};
                a = __builtin_elementwise_fma(tt, As2[v * 4 + m], a);
            }
            a = (a * 0.25f) + 128.f;
            O[2 * m] = a[0]; O[2 * m + 1] = a[1];
        }
        // write back in place (regions disjoint per group)
        if (isY) {
            int by = g >> 1, bx = g & 1;
            *(f4*)&W[OY + (by * 8 + j) * 20 + bx * 8]     = (f4){O[0], O[1], O[2], O[3]};
            *(f4*)&W[OY + (by * 8 + j) * 20 + bx * 8 + 4] = (f4){O[4], O[5], O[6], O[7]};
        } else {
            int ob = (g == 4) ? OCB : OCR;
            *(f4*)&W[ob + j * 12]     = (f4){O[0], O[1], O[2], O[3]};
            *(f4*)&W[ob + j * 12 + 4] = (f4){O[4], O[5], O[6], O[7]};
        }
    }
    asm volatile("" ::: "memory");

    // ---- output: upsample chroma, YCbCr->RGB (no fma), clip, *INV255
    {
        const float INV255 = 1.0f / 255.0f;
        f4 y2 = *(const f4*)&W[OY + srow * 20 + sc4];
        int cy = srow >> 1, cc = sc4 >> 1;
        float cb0 = W[OCB + cy * 12 + cc]     - 128.f;   // +SHIFT2 separate add
        float cb1 = W[OCB + cy * 12 + cc + 1] - 128.f;
        float cr0 = W[OCR + cy * 12 + cc]     - 128.f;
        float cr1 = W[OCR + cy * 12 + cc + 1] - 128.f;
        f4 cbm = {cb0, cb0, cb1, cb1};
        f4 crm = {cr0, cr0, cr1, cr1};
        f4 z = 0.f, m255 = 255.f;
        f4 rv = y2 + (crm * 1.402f);
        f4 gv = (y2 + (cbm * -0.344136f)) + (crm * -0.714136f);
        f4 bv = y2 + (cbm * 1.772f);
        rv = __builtin_elementwise_max(__builtin_elementwise_min(rv, m255), z) * INV255;
        gv = __builtin_elementwise_max(__builtin_elementwise_min(gv, m255), z) * INV255;
        bv = __builtin_elementwise_max(__builtin_elementwise_min(bv, m255), z) * INV255;
        __builtin_nontemporal_store(rv, (f4*)(out + gbase));
        __builtin_nontemporal_store(gv, (f4*)(out + gbase + plane));
        __builtin_nontemporal_store(bv, (f4*)(out + gbase + 2 * plane));
    }
}

extern "C" void kernel_launch(void* const* d_in, const int* in_sizes, int n_in,
                              void* d_out, int out_size, void* d_ws, size_t ws_size,
                              hipStream_t stream)
{
    const float* x = (const float*)d_in[0];
    float* o = (float*)d_out;
    int batch  = in_sizes[0] / (3 * HH * WW);   // 32
    int blocks = batch * 1024 / 4;              // 8192 (4 tiles per block, 1/wave)
    jpeg_fused<<<blocks, 256, 0, stream>>>(x, o);
}

// Round 16
// 40.679 us; speedup vs baseline: 1.1232x; 1.1232x over previous
//
#include <hip/hip_runtime.h>
#include <math.h>

#define HH 512
#define WW 512

typedef float f2 __attribute__((ext_vector_type(2)));
typedef float f4 __attribute__((ext_vector_type(4)));

// per-wave LDS slice layout (word offsets)
#define YS2  36                   // Y row stride
#define CS2  18                   // chroma row stride
#define OY   0                    // Y 16 x 36                     [0,576)
#define OCB  576                  // Cb means 8 x 18 (+128 form)   [576,720)
#define OCR  720                  // Cr means 8 x 18               [720,864)
#define OSCR 864                  // scratch 6 x 68 (basis overlaid)[864,1272)
#define OAB  OSCR                 // basis lives here until scratch is needed
#define WSZ  1272                 // 5088 B/wave -> 20352 B per 4-wave block

static __device__ __forceinline__ f4 vclamp01x255(f4 v) {
    f4 z = 0.f, one = 1.f;
    return __builtin_elementwise_max(__builtin_elementwise_min(v, one), z) * 255.f;
}

__device__ __constant__ float YTAB[64] = {
    16,11,10,16,24,40,51,61,
    12,12,14,19,26,58,60,55,
    14,13,16,24,40,57,69,56,
    14,17,22,29,51,87,80,62,
    18,22,37,56,68,109,103,77,
    24,35,55,64,81,104,113,92,
    49,64,78,87,103,121,120,101,
    72,92,95,98,112,100,103,99};
__device__ __constant__ float CTAB[64] = {
    17,18,24,47,99,99,99,99,
    18,21,26,66,99,99,99,99,
    24,26,56,99,99,99,99,99,
    47,66,99,99,99,99,99,99,
    99,99,99,99,99,99,99,99,
    99,99,99,99,99,99,99,99,
    99,99,99,99,99,99,99,99,
    99,99,99,99,99,99,99,99};

// WAVE-AUTONOMOUS, COALESCING-FIXED: one wave = one 32x16 tile-PAIR
// (8 Y + 2 Cb + 2 Cr blocks, DCT in 2 passes of 6 lane-groups). 4 independent
// waves per 256-thread block, ZERO barriers (wave-private LDS, in-order DS).
// Global I/O: lane handles a 2-row x 4-col quad -> every row segment is
// 8 lanes x 16B = 128B = full cache line (fixes R15's 64B write split).
// Chroma means computed IN-REGISTER at staging (lane owns complete 2x2
// quads) -> full-res chroma never staged. 20352B LDS/block -> 8 blocks/CU =
// 32 waves/CU. Bit-critical pre-round math identical to verified R8/R10-R13:
//  - color: left-assoc mul/add, NO fma; chroma mean paired (s01+s23)/4
//  - DCT: two ascending-k fmaf chains (BLAS sgemm semantics), fp32 T1
//  - quantize: IEEE fp32 div by qt, rintf (half-even), cube fp32
// Post-round relaxed (*INV255, nontemporal full-line stores).
__global__ __launch_bounds__(256) void jpeg_fused(const float* __restrict__ in,
                                                  float* __restrict__ out)
{
#pragma clang fp contract(off)
    __shared__ float Wall[4][WSZ];

    const int tid  = threadIdx.x;
    const int wid  = tid >> 6;
    const int lane = tid & 63;
    float* W = Wall[wid];

    const int wv    = blockIdx.x * 4 + wid;   // global wave id = tile-pair id
    const int b     = wv >> 9;                // 512 pairs per image
    const int strip = (wv >> 4) & 31;         // 0..31
    const int pairc = wv & 15;                // 0..15
    const int h0    = strip * 16;
    const int w0    = pairc * 32;
    const size_t plane = (size_t)HH * WW;

    // lane -> 2-row x 4-col quad
    const int rp  = lane >> 3;                // row pair 0..7
    const int pr  = rp * 2;
    const int c4  = (lane & 7) * 4;           // col 0..28
    const size_t gbase = ((size_t)b * 3 * HH + (size_t)(h0 + pr)) * WW + (w0 + c4);

    // ---- issue all 6 global loads first (latency hidden by basis build)
    f4 Lr0 = *(const f4*)(in + gbase);
    f4 Lr1 = *(const f4*)(in + gbase + WW);
    f4 Lg0 = *(const f4*)(in + gbase + plane);
    f4 Lg1 = *(const f4*)(in + gbase + plane + WW);
    f4 Lb0 = *(const f4*)(in + gbase + 2 * plane);
    f4 Lb1 = *(const f4*)(in + gbase + 2 * plane + WW);

    // ---- basis (np-exact: int mult, fp64 pi-mult/div, fp64 cos, fp32 cast)
    {
        int x = lane >> 3, u = lane & 7;
        double arg = (double)((2 * x + 1) * u) * 3.14159265358979323846 / 16.0;
        W[OAB + lane] = (float)cos(arg);
    }
    // basis pairs -> wave-uniform f2 (SGPRs); overlaps load latency
    f2 As2[32];
#pragma unroll
    for (int k = 0; k < 32; ++k) {
        As2[k][0] = __int_as_float(__builtin_amdgcn_readfirstlane(__float_as_int(W[OAB + 2 * k])));
        As2[k][1] = __int_as_float(__builtin_amdgcn_readfirstlane(__float_as_int(W[OAB + 2 * k + 1])));
    }
    asm volatile("" ::: "memory");     // basis consumed before scratch reuse

    // ---- stage: clip*255, YCbCr (noblas: left-assoc mul/add, NO fma);
    // chroma means in-register (lane owns both full 2x2 quads)
    {
        f4 r0 = vclamp01x255(Lr0), r1 = vclamp01x255(Lr1);
        f4 g0 = vclamp01x255(Lg0), g1 = vclamp01x255(Lg1);
        f4 b0 = vclamp01x255(Lb0), b1 = vclamp01x255(Lb1);
        f4 y0  = ((r0 * 0.299f)     + (g0 * 0.587f))     + (b0 * 0.114f);
        f4 y1  = ((r1 * 0.299f)     + (g1 * 0.587f))     + (b1 * 0.114f);
        f4 cb0 = ((r0 * -0.168736f) + (g0 * -0.331264f)) + (b0 * 0.5f);
        f4 cb1 = ((r1 * -0.168736f) + (g1 * -0.331264f)) + (b1 * 0.5f);
        f4 cr0 = ((r0 * 0.5f)       + (g0 * -0.418688f)) + (b0 * -0.081312f);
        f4 cr1 = ((r1 * 0.5f)       + (g1 * -0.418688f)) + (b1 * -0.081312f);
        cb0 = cb0 + 128.f; cb1 = cb1 + 128.f;   // +SHIFT1 separate rn add
        cr0 = cr0 + 128.f; cr1 = cr1 + 128.f;
        y0 = y0 - 128.f;  y1 = y1 - 128.f;      // channel does blocks-128
        *(f4*)&W[OY + pr * YS2 + c4]       = y0;
        *(f4*)&W[OY + (pr + 1) * YS2 + c4] = y1;
        // np multi-axis mean: paired (p00+p01)+(p10+p11), true-div by 4
        f2 mb, mr;
        {
            float s01 = cb0.x + cb0.y, s23 = cb1.x + cb1.y;
            mb[0] = (s01 + s23) / 4.0f;
            float t01 = cb0.z + cb0.w, t23 = cb1.z + cb1.w;
            mb[1] = (t01 + t23) / 4.0f;
        }
        {
            float s01 = cr0.x + cr0.y, s23 = cr1.x + cr1.y;
            mr[0] = (s01 + s23) / 4.0f;
            float t01 = cr0.z + cr0.w, t23 = cr1.z + cr1.w;
            mr[1] = (t01 + t23) / 4.0f;
        }
        *(f2*)&W[OCB + rp * CS2 + (lane & 7) * 2] = mb;
        *(f2*)&W[OCR + rp * CS2 + (lane & 7) * 2] = mr;
    }
    asm volatile("" ::: "memory");

    // ---- DCT / quantize / IDCT: 12 blocks in 2 passes of 6 lane-groups
    const int g = lane >> 3, j = lane & 7;
#pragma unroll
    for (int pass = 0; pass < 2; ++pass) {
        if (g < 6) {
            const int it   = pass * 6 + g;       // 0..11
            const bool isY = (it < 8);
            float* scr = &W[OSCR + g * 68];

            float X[8];
            int by = 0, bx = 0, ob = 0;
            if (isY) {
                by = it >> 2; bx = it & 3;
#pragma unroll
                for (int x = 0; x < 8; ++x)
                    X[x] = W[OY + (by * 8 + x) * YS2 + bx * 8 + j];
            } else {
                ob = (it < 10) ? OCB : OCR;
                bx = (it < 10) ? (it - 8) : (it - 10);
#pragma unroll
                for (int x = 0; x < 8; ++x)
                    X[x] = W[ob + x * CS2 + bx * 8 + j] - 128.f;
            }

            // pass1 (contract x): T1[y=j][u], ascending-x fmaf chains, packed
            f2 Tv[4];
#pragma unroll
            for (int m = 0; m < 4; ++m) {
                f2 a = {0.f, 0.f};
#pragma unroll
                for (int x = 0; x < 8; ++x) {
                    f2 xx = {X[x], X[x]};
                    a = __builtin_elementwise_fma(xx, As2[x * 4 + m], a);
                }
                Tv[m] = a;
            }
#pragma unroll
            for (int m = 0; m < 4; ++m) {
                scr[(2 * m) * 8 + j]     = Tv[m][0];
                scr[(2 * m + 1) * 8 + j] = Tv[m][1];
            }
            float Tt[8];
            {
                float4 a = *(const float4*)&scr[j * 8];
                float4 c = *(const float4*)&scr[j * 8 + 4];
                Tt[0] = a.x; Tt[1] = a.y; Tt[2] = a.z; Tt[3] = a.w;
                Tt[4] = c.x; Tt[5] = c.y; Tt[6] = c.z; Tt[7] = c.w;
            }
            // pass2 (contract y): raw[u=j][v], ascending-y packed chains
            float R[8];
#pragma unroll
            for (int m = 0; m < 4; ++m) {
                f2 a = {0.f, 0.f};
#pragma unroll
                for (int y = 0; y < 8; ++y) {
                    f2 tt = {Tt[y], Tt[y]};
                    a = __builtin_elementwise_fma(tt, As2[y * 4 + m], a);
                }
                R[2 * m] = a[0]; R[2 * m + 1] = a[1];
            }
            // quantize row u=j (bit-critical: IEEE div, rintf), dequant, *a2
            const float* QT = isY ? YTAB : CTAB;
            float qt[8];
            {
                float4 a = *(const float4*)&QT[j * 8];
                float4 c = *(const float4*)&QT[j * 8 + 4];
                qt[0] = a.x; qt[1] = a.y; qt[2] = a.z; qt[3] = a.w;
                qt[4] = c.x; qt[5] = c.y; qt[6] = c.z; qt[7] = c.w;
            }
            const float RC = 0.70710678118654752440f;
            float au = (j == 0) ? RC : 1.0f;
            float G[8];
#pragma unroll
            for (int v = 0; v < 8; ++v) {
                float av    = (v == 0) ? RC : 1.0f;
                float a2    = au * av;             // ALPHA2 fp32 product
                float scale = a2 * 0.25f;          // _SCALE
                float dct   = scale * R[v];
                float xq    = dct / qt[v];         // IEEE fp32 divide
                float rd    = rintf(xq);           // half-to-even
                float d     = xq - rd;
                float cube  = (d * d) * d;
                float qq    = rd + cube;
                float deq   = qq * qt[v];
                G[v] = deq * a2;
            }
#pragma unroll
            for (int v = 0; v < 8; ++v) scr[v * 8 + j] = G[v];
            float Gt[8];
            {
                float4 a = *(const float4*)&scr[j * 8];
                float4 c = *(const float4*)&scr[j * 8 + 4];
                Gt[0] = a.x; Gt[1] = a.y; Gt[2] = a.z; Gt[3] = a.w;
                Gt[4] = c.x; Gt[5] = c.y; Gt[6] = c.z; Gt[7] = c.w;
            }
            // IDCT pass1 (contract u): T2[x][v=j], packed over x pairs
            f2 T2v[4];
#pragma unroll
            for (int m = 0; m < 4; ++m) {
                f2 a = {0.f, 0.f};
#pragma unroll
                for (int u = 0; u < 8; ++u) {
                    f2 gg = {Gt[u], Gt[u]};
                    a = __builtin_elementwise_fma(gg, As2[u * 4 + m], a);
                }
                T2v[m] = a;
            }
#pragma unroll
            for (int m = 0; m < 4; ++m) {
                scr[(2 * m) * 8 + j]     = T2v[m][0];
                scr[(2 * m + 1) * 8 + j] = T2v[m][1];
            }
            float T2t[8];
            {
                float4 a = *(const float4*)&scr[j * 8];
                float4 c = *(const float4*)&scr[j * 8 + 4];
                T2t[0] = a.x; T2t[1] = a.y; T2t[2] = a.z; T2t[3] = a.w;
                T2t[4] = c.x; T2t[5] = c.y; T2t[6] = c.z; T2t[7] = c.w;
            }
            // IDCT pass2 (contract v): out[x=j][y] = 0.25*sum + 128, packed
            float O[8];
#pragma unroll
            for (int m = 0; m < 4; ++m) {
                f2 a = {0.f, 0.f};
#pragma unroll
                for (int v = 0; v < 8; ++v) {
                    f2 tt = {T2t[v], T2t[v]};
                    a = __builtin_elementwise_fma(tt, As2[v * 4 + m], a);
                }
                a = (a * 0.25f) + 128.f;
                O[2 * m] = a[0]; O[2 * m + 1] = a[1];
            }
            // write back in place (regions disjoint per item)
            if (isY) {
                *(f4*)&W[OY + (by * 8 + j) * YS2 + bx * 8]     = (f4){O[0], O[1], O[2], O[3]};
                *(f4*)&W[OY + (by * 8 + j) * YS2 + bx * 8 + 4] = (f4){O[4], O[5], O[6], O[7]};
            } else {
                *(f4*)&W[ob + j * CS2 + bx * 8]     = (f4){O[0], O[1], O[2], O[3]};
                *(f4*)&W[ob + j * CS2 + bx * 8 + 4] = (f4){O[4], O[5], O[6], O[7]};
            }
        }
        asm volatile("" ::: "memory");     // pass boundary (scratch reuse)
    }

    // ---- output: upsample chroma, YCbCr->RGB (no fma), clip, *INV255,
    // nontemporal full-line stores
    {
        const float INV255 = 1.0f / 255.0f;
        f4 ya = *(const f4*)&W[OY + pr * YS2 + c4];
        f4 yb = *(const f4*)&W[OY + (pr + 1) * YS2 + c4];
        f2 cbp = *(const f2*)&W[OCB + rp * CS2 + (lane & 7) * 2];
        f2 crp = *(const f2*)&W[OCR + rp * CS2 + (lane & 7) * 2];
        float cb0 = cbp[0] - 128.f, cb1 = cbp[1] - 128.f;   // +SHIFT2 sep add
        float cr0 = crp[0] - 128.f, cr1 = crp[1] - 128.f;
        f4 cbm = {cb0, cb0, cb1, cb1};
        f4 crm = {cr0, cr0, cr1, cr1};
        f4 z = 0.f, m255 = 255.f;
#pragma unroll
        for (int row = 0; row < 2; ++row) {
            f4 yy = row ? yb : ya;
            f4 rv = yy + (crm * 1.402f);
            f4 gv = (yy + (cbm * -0.344136f)) + (crm * -0.714136f);
            f4 bv = yy + (cbm * 1.772f);
            rv = __builtin_elementwise_max(__builtin_elementwise_min(rv, m255), z) * INV255;
            gv = __builtin_elementwise_max(__builtin_elementwise_min(gv, m255), z) * INV255;
            bv = __builtin_elementwise_max(__builtin_elementwise_min(bv, m255), z) * INV255;
            size_t base = gbase + (size_t)row * WW;
            __builtin_nontemporal_store(rv, (f4*)(out + base));
            __builtin_nontemporal_store(gv, (f4*)(out + base + plane));
            __builtin_nontemporal_store(bv, (f4*)(out + base + 2 * plane));
        }
    }
}

extern "C" void kernel_launch(void* const* d_in, const int* in_sizes, int n_in,
                              void* d_out, int out_size, void* d_ws, size_t ws_size,
                              hipStream_t stream)
{
    const float* x = (const float*)d_in[0];
    float* o = (float*)d_out;
    int batch  = in_sizes[0] / (3 * HH * WW);   // 32
    int blocks = batch * 512 / 4;               // 4096 (4 tile-pairs per block)
    jpeg_fused<<<blocks, 256, 0, stream>>>(x, o);
}